// Round 14
// baseline (204.613 us; speedup 1.0000x reference)
//
#include <hip/hip_runtime.h>
#include <hip/hip_bf16.h>
#include <math.h>

#define KNN 5
#define K3 27
#define CENTER 13
#define NCLASSES 21
#define DIM_D 32
#define DIM_H 128
#define DIM_W 2048

#define RADIX 256
#define BIN_PTS 2048
#define SEG_TILE 2048

// Sort plan (grouping-exact, deterministic):
//   pass 1 (512 thr): bin by seg = y<<1 | x>>10   (256 bins, global cursors)
//   pass 2 (1024 thr): one block per segment; bin by b8 = (z<<3)|(x>>7 & 7)
//   Final order: (y, x10, z, x9..7) — measured R10-R12: main FETCH 45 MB.

// 4B-aligned vector types for unaligned-row loads (dword-aligned dwordx4)
typedef float float4u __attribute__((ext_vector_type(4), aligned(4)));
typedef int   int4u   __attribute__((ext_vector_type(4), aligned(4)));

__device__ __forceinline__ unsigned seg_of_xy(int x, int y) {
    return ((unsigned)y << 1) | ((unsigned)x >> 10);
}
__device__ __forceinline__ unsigned seg_of_wy(unsigned wy) {
    return (((wy >> 11) & 0x7Fu) << 1) | ((wy >> 10) & 1u);
}
__device__ __forceinline__ unsigned b8_of_wy(unsigned wy) {
    return (((wy >> 18) & 31u) << 3) | ((wy >> 7) & 7u);
}

// ---------------- seg histogram ----------------
__global__ __launch_bounds__(256) void hist0_kernel(
    const int* __restrict__ px, const int* __restrict__ py,
    unsigned* __restrict__ h0, int P)
{
    __shared__ unsigned lh0[RADIX];
    int t = threadIdx.x;
    lh0[t] = 0;
    __syncthreads();
    int base4 = blockIdx.x * 1024 + t;
#pragma unroll
    for (int g = 0; g < 4; ++g) {
        int i4 = base4 + g * 256;
        int i0 = i4 * 4;
        if (i0 + 3 < P) {
            int4 X = ((const int4*)px)[i4];
            int4 Y = ((const int4*)py)[i4];
            atomicAdd(&lh0[seg_of_xy(X.x, Y.x)], 1u);
            atomicAdd(&lh0[seg_of_xy(X.y, Y.y)], 1u);
            atomicAdd(&lh0[seg_of_xy(X.z, Y.z)], 1u);
            atomicAdd(&lh0[seg_of_xy(X.w, Y.w)], 1u);
        } else {
            for (int i = i0; i < P; ++i)
                atomicAdd(&lh0[seg_of_xy(px[i], py[i])], 1u);
        }
    }
    __syncthreads();
    if (lh0[t]) atomicAdd(&h0[t], lh0[t]);
}

// exclusive scan of 256 entries; result to BOTH h (pass-1 cursors) and hbase
__global__ __launch_bounds__(256) void scan256_dup_kernel(
    unsigned* __restrict__ h, unsigned* __restrict__ hbase)
{
    __shared__ unsigned ws[4];
    int t = threadIdx.x, lane = t & 63, wid = t >> 6;
    unsigned a = h[t], ia = a;
#pragma unroll
    for (int off = 1; off < 64; off <<= 1) {
        unsigned v = __shfl_up(ia, off);
        if (lane >= off) ia += v;
    }
    if (lane == 63) ws[wid] = ia;
    __syncthreads();
    unsigned b = 0;
#pragma unroll
    for (int w = 0; w < 4; ++w) b += (w < wid) ? ws[w] : 0u;
    unsigned excl = b + ia - a;
    h[t] = excl;
    hbase[t] = excl;
}

// ---------------- pass 1: bin by seg, 512 threads ----------------
struct BinShared {
    unsigned lh[RADIX];
    unsigned lscan[RADIX];
    unsigned gbase[RADIX];
    unsigned wsum[4];
    uint4 stage[BIN_PTS];   // 32 KB
};

__global__ __launch_bounds__(512) void bin_pass1_kernel(
    const float* __restrict__ ur, const int* __restrict__ px,
    const int* __restrict__ py, const int* __restrict__ pz,
    unsigned* __restrict__ g0, uint4* __restrict__ outp, int P)
{
    __shared__ BinShared S;
    int t = threadIdx.x, lane = t & 63, wid = t >> 6;
    int bstart = blockIdx.x * BIN_PTS;
    int n = min(BIN_PTS, P - bstart);
    if (t < RADIX) S.lh[t] = 0;
    __syncthreads();

    uint4 pay[4];
    unsigned rk[4], dg[4];
    {
        int i4 = (bstart >> 2) + t;
        int i0 = i4 * 4;
        if (i0 + 3 < P) {
            int4 X = ((const int4*)px)[i4];
            int4 Y = ((const int4*)py)[i4];
            int4 Z = ((const int4*)pz)[i4];
            float4 U = ((const float4*)ur)[i4];
            int xs[4] = {X.x, X.y, X.z, X.w};
            int ys[4] = {Y.x, Y.y, Y.z, Y.w};
            int zs[4] = {Z.x, Z.y, Z.z, Z.w};
            float us[4] = {U.x, U.y, U.z, U.w};
#pragma unroll
            for (int c = 0; c < 4; ++c) {
                dg[c] = seg_of_xy(xs[c], ys[c]);
                rk[c] = atomicAdd(&S.lh[dg[c]], 1u);
                pay[c] = make_uint4(__float_as_uint(us[c]),
                    (unsigned)xs[c] | ((unsigned)ys[c] << 11) | ((unsigned)zs[c] << 18),
                    (unsigned)(i0 + c), 0u);
            }
        } else {
#pragma unroll
            for (int c = 0; c < 4; ++c) {
                int gi = i0 + c;
                if (gi < P) {
                    int x = px[gi], y = py[gi], z = pz[gi];
                    dg[c] = seg_of_xy(x, y);
                    rk[c] = atomicAdd(&S.lh[dg[c]], 1u);
                    pay[c] = make_uint4(__float_as_uint(ur[gi]),
                        (unsigned)x | ((unsigned)y << 11) | ((unsigned)z << 18),
                        (unsigned)gi, 0u);
                } else {
                    dg[c] = 0xFFFFFFFFu;
                }
            }
        }
    }
    __syncthreads();

    {
        unsigned c0 = (t < RADIX) ? S.lh[t] : 0u;
        unsigned inc = c0;
#pragma unroll
        for (int off = 1; off < 64; off <<= 1) {
            unsigned v = __shfl_up(inc, off);
            if (lane >= off) inc += v;
        }
        if (t < RADIX && lane == 63) S.wsum[wid] = inc;
        __syncthreads();
        if (t < RADIX) {
            unsigned wb = 0;
#pragma unroll
            for (int w = 0; w < 4; ++w) wb += (w < wid) ? S.wsum[w] : 0u;
            S.lscan[t] = wb + inc - c0;
            S.gbase[t] = c0 ? atomicAdd(&g0[t], c0) : 0u;
        }
    }
    __syncthreads();
#pragma unroll
    for (int c = 0; c < 4; ++c)
        if (dg[c] != 0xFFFFFFFFu)
            S.stage[S.lscan[dg[c]] + rk[c]] = pay[c];
    __syncthreads();
#pragma unroll
    for (int j = 0; j < 4; ++j) {
        int s = j * 512 + t;
        if (s < n) {
            uint4 v = S.stage[s];
            unsigned d = seg_of_wy(v.y);
            unsigned pos = S.gbase[d] + ((unsigned)s - S.lscan[d]);
            outp[pos] = v;
        }
    }
}

// ---------------- pass 2: per-segment (z,x97) scatter, 1024 threads ----------------
__global__ __launch_bounds__(1024) void pass2b_kernel(
    const uint4* __restrict__ inp, const unsigned* __restrict__ segBase,
    uint4* __restrict__ outp, int P)
{
    __shared__ unsigned bh[RADIX];
    __shared__ unsigned cur[RADIX];
    __shared__ unsigned lz[RADIX];
    __shared__ unsigned lsc[RADIX];
    __shared__ unsigned wsum[4];
    __shared__ uint4 stage[SEG_TILE];   // 32 KB

    int b = blockIdx.x;
    unsigned s0 = segBase[b];
    unsigned s1 = (b == RADIX - 1) ? (unsigned)P : segBase[b + 1];
    int t = threadIdx.x, lane = t & 63, wid = t >> 6;

    if (t < RADIX) bh[t] = 0;
    __syncthreads();

    for (unsigned i = s0 + t; i < s1; i += 1024)
        atomicAdd(&bh[b8_of_wy(inp[i].y)], 1u);
    __syncthreads();

    {
        unsigned c0 = (t < RADIX) ? bh[t] : 0u;
        unsigned inc = c0;
#pragma unroll
        for (int off = 1; off < 64; off <<= 1) {
            unsigned v = __shfl_up(inc, off);
            if (lane >= off) inc += v;
        }
        if (t < RADIX && lane == 63) wsum[wid] = inc;
        __syncthreads();
        if (t < RADIX) {
            unsigned wb = 0;
#pragma unroll
            for (int w = 0; w < 4; ++w) wb += (w < wid) ? wsum[w] : 0u;
            cur[t] = s0 + wb + inc - c0;
        }
    }
    __syncthreads();

    for (unsigned tb = s0; tb < s1; tb += SEG_TILE) {
        unsigned m = min((unsigned)SEG_TILE, s1 - tb);
        if (t < RADIX) lz[t] = 0;
        __syncthreads();
        uint4 pay[2];
        unsigned rk[2], zz[2];
#pragma unroll
        for (int j = 0; j < 2; ++j) {
            int s = j * 1024 + t;
            if (s < (int)m) {
                uint4 v = inp[tb + (unsigned)s];
                pay[j] = v;
                zz[j] = b8_of_wy(v.y);
                rk[j] = atomicAdd(&lz[zz[j]], 1u);
            } else {
                zz[j] = 0xFFFFFFFFu;
            }
        }
        __syncthreads();
        {
            unsigned c0 = (t < RADIX) ? lz[t] : 0u;
            unsigned inc = c0;
#pragma unroll
            for (int off = 1; off < 64; off <<= 1) {
                unsigned v = __shfl_up(inc, off);
                if (lane >= off) inc += v;
            }
            if (t < RADIX && lane == 63) wsum[wid] = inc;
            __syncthreads();
            if (t < RADIX) {
                unsigned wb = 0;
#pragma unroll
                for (int w = 0; w < 4; ++w) wb += (w < wid) ? wsum[w] : 0u;
                lsc[t] = wb + inc - c0;
            }
        }
        __syncthreads();
#pragma unroll
        for (int j = 0; j < 2; ++j)
            if (zz[j] != 0xFFFFFFFFu)
                stage[lsc[zz[j]] + rk[j]] = pay[j];
        __syncthreads();
#pragma unroll
        for (int j = 0; j < 2; ++j) {
            int s = j * 1024 + t;
            if (s < (int)m) {
                uint4 v = stage[s];
                unsigned d = b8_of_wy(v.y);
                outp[cur[d] + ((unsigned)s - lsc[d])] = v;
            }
        }
        __syncthreads();
        if (t < RADIX) cur[t] += lz[t];
        __syncthreads();
    }
}

// ---------------- KNN body: fully-prefetched rows (pr + pa), no dependent gathers ----
__device__ __forceinline__ int pick9(const int pk[9], int r) {
    int v = pk[0];
#pragma unroll
    for (int i = 1; i < 9; ++i) v = (r == i) ? pk[i] : v;
    return v;
}

__device__ __forceinline__ void bev_knn_body(
    const float* __restrict__ pr, const int* __restrict__ pa,
    float u, int x, int y, int z, int oidx, int* __restrict__ out)
{
    // One 4B-aligned 16B load per (dz,dy) row for BOTH pr and pa, covering
    // x-1..x+2. xo clamped inside the row; uniform shift s remaps lanes:
    //   needed val_j = L[s+j], j=0..2, with L[-1]=L[4]=0 (zero padding).
    int xo = min(max(x - 1, 0), DIM_W - 4);
    int s = x - 1 - xo;             // -1 (x=0), 0 (common), 1 (x=2046), 2 (x=2047)

    float dist[K3];
    int pk[9];                      // per-row packed classes c0|c1<<8|c2<<16
#pragma unroll
    for (int r = 0; r < 9; ++r) {
        const int dz = r / 3 - 1;
        const int dy = r % 3 - 1;
        int zz = z + dz, yy = y + dy;
        bool ok = ((unsigned)zz < (unsigned)DIM_D) &
                  ((unsigned)yy < (unsigned)DIM_H);
        int row = ok ? (zz * DIM_H + yy) : 0;
        size_t rb = (((size_t)row) << 11) + xo;
        float4u l = *(const float4u*)(pr + rb);
        int4u   a = *(const int4u*)(pa + rb);
        float a0 = ok ? l.x : 0.f;
        float a1 = ok ? l.y : 0.f;
        float a2 = ok ? l.z : 0.f;
        float a3 = ok ? l.w : 0.f;
        int   c0 = ok ? a.x : 0;
        int   c1 = ok ? a.y : 0;
        int   c2 = ok ? a.z : 0;
        int   c3 = ok ? a.w : 0;
        // v_j / cc_j = L[s+j]
        float v0 = (s == 0) ? a0 : ((s == -1) ? 0.f : ((s == 1) ? a1 : a2));
        float v1 = (s == 0) ? a1 : ((s == -1) ? a0 : ((s == 1) ? a2 : a3));
        float v2 = (s == 0) ? a2 : ((s == -1) ? a1 : ((s == 1) ? a3 : 0.f));
        int  cc0 = (s == 0) ? c0 : ((s == -1) ? 0   : ((s == 1) ? c1 : c2));
        int  cc1 = (s == 0) ? c1 : ((s == -1) ? c0  : ((s == 1) ? c2 : c3));
        int  cc2 = (s == 0) ? c2 : ((s == -1) ? c1  : ((s == 1) ? c3 : 0));
        v0 = (v0 < 0.f) ? INFINITY : v0;
        v1 = (v1 < 0.f) ? INFINITY : v1;
        v2 = (v2 < 0.f) ? INFINITY : v2;
        int k = r * 3;
        dist[k + 0] = fabsf(v0 - u);
        dist[k + 1] = (k + 1 == CENTER) ? 0.0f : fabsf(v1 - u);
        dist[k + 2] = fabsf(v2 - u);
        pk[r] = (cc0 & 0xFF) | ((cc1 & 0xFF) << 8) | ((cc2 & 0xFF) << 16);
    }

    // top-5 smallest, ties -> lower flat index (lax.top_k semantics)
    float bd[KNN];
    int   bk[KNN];
#pragma unroll
    for (int j = 0; j < KNN; ++j) { bd[j] = INFINITY; bk[j] = -1; }
#pragma unroll
    for (int k = 0; k < K3; ++k) {
        float dcur = dist[k];
        int   kcur = k;
#pragma unroll
        for (int j = 0; j < KNN; ++j) {
            bool take = dcur < bd[j];
            float td = bd[j]; int tk = bk[j];
            bd[j] = take ? dcur : bd[j];
            bk[j] = take ? kcur : bk[j];
            dcur  = take ? td : dcur;
            kcur  = take ? tk : kcur;
        }
    }

    // classes of the 5 winners from the prefetched packed rows + cutoff
    int votes[KNN];
#pragma unroll
    for (int j = 0; j < KNN; ++j) {
        int k = bk[j];
        int r = k / 3;             // compiler: magic-mul
        int c = pick9(pk, r);
        int cls = (c >> (8 * (k - r * 3))) & 0xFF;
        cls = (bd[j] > 1.0f) ? NCLASSES : cls;
        votes[j] = cls;
    }

    int best_cnt = 0, best_cls = 1;
#pragma unroll
    for (int j = 0; j < KNN; ++j) {
        int v = votes[j];
        if (v >= 1 && v <= NCLASSES - 1) {
            int cnt = 0;
#pragma unroll
            for (int i = 0; i < KNN; ++i) cnt += (votes[i] == v) ? 1 : 0;
            if (cnt > best_cnt || (cnt == best_cnt && v < best_cls)) {
                best_cnt = cnt;
                best_cls = v;
            }
        }
    }
    out[oidx] = best_cls;
}

__device__ __forceinline__ int swizzle_block(int b, int nb) {
    if ((nb & 7) == 0) {
        int per = nb >> 3;
        return (b & 7) * per + (b >> 3);
    }
    return b;
}

__global__ __launch_bounds__(256) void bev_knn_aos_kernel(
    const float* __restrict__ pr, const int* __restrict__ pa,
    const uint4* __restrict__ payload, int* __restrict__ out, int P)
{
    int lb = swizzle_block(blockIdx.x, gridDim.x);
    int p = lb * blockDim.x + threadIdx.x;
    if (p >= P) return;
    uint4 w = payload[p];
    float u = __uint_as_float(w.x);
    int x = (int)(w.y & 0x7FFu);
    int y = (int)((w.y >> 11) & 0x7Fu);
    int z = (int)((w.y >> 18) & 0x1Fu);
    bev_knn_body(pr, pa, u, x, y, z, (int)w.z, out);
}

__global__ __launch_bounds__(256) void bev_knn_direct_kernel(
    const float* __restrict__ pr, const int* __restrict__ pa,
    const float* __restrict__ ur, const int* __restrict__ px,
    const int* __restrict__ py, const int* __restrict__ pz,
    int* __restrict__ out, int P)
{
    int p = blockIdx.x * blockDim.x + threadIdx.x;
    if (p >= P) return;
    bev_knn_body(pr, pa, ur[p], px[p], py[p], pz[p], p, out);
}

extern "C" void kernel_launch(void* const* d_in, const int* in_sizes, int n_in,
                              void* d_out, int out_size, void* d_ws, size_t ws_size,
                              hipStream_t stream) {
    const float* pr = (const float*)d_in[0];
    const float* ur = (const float*)d_in[1];
    const int*   pa = (const int*)d_in[2];
    const int*   px = (const int*)d_in[3];
    const int*   py = (const int*)d_in[4];
    const int*   pz = (const int*)d_in[5];
    int* out = (int*)d_out;
    int P = in_sizes[1];
    int gridH = (P + 4095) / 4096;
    int gridB = (P + BIN_PTS - 1) / BIN_PTS;
    int gridD = (P + 255) / 256;

    size_t h_b   = (size_t)RADIX * 4;
    size_t hb_b  = (size_t)RADIX * 4;
    size_t p_off = (h_b + hb_b + 15) & ~(size_t)15;
    size_t pay_b = (size_t)P * 16;
    size_t need  = p_off + 2 * pay_b;

    if (ws_size >= need) {
        char* ws = (char*)d_ws;
        unsigned* h0cur  = (unsigned*)ws;
        unsigned* h0base = (unsigned*)(ws + h_b);
        uint4*    pay1   = (uint4*)(ws + p_off);
        uint4*    pay2   = (uint4*)(ws + p_off + pay_b);

        hipMemsetAsync(h0cur, 0, h_b, stream);
        hist0_kernel<<<gridH, 256, 0, stream>>>(px, py, h0cur, P);
        scan256_dup_kernel<<<1, 256, 0, stream>>>(h0cur, h0base);
        bin_pass1_kernel<<<gridB, 512, 0, stream>>>(ur, px, py, pz,
                                                    h0cur, pay1, P);
        pass2b_kernel<<<RADIX, 1024, 0, stream>>>(pay1, h0base, pay2, P);
        bev_knn_aos_kernel<<<gridD, 256, 0, stream>>>(pr, pa, pay2, out, P);
    } else {
        bev_knn_direct_kernel<<<gridD, 256, 0, stream>>>(pr, pa, ur, px, py,
                                                         pz, out, P);
    }
}

// Round 15
// 194.813 us; speedup vs baseline: 1.0503x; 1.0503x over previous
//
#include <hip/hip_runtime.h>
#include <hip/hip_bf16.h>
#include <math.h>

#define KNN 5
#define K3 27
#define CENTER 13
#define NCLASSES 21
#define DIM_D 32
#define DIM_H 128
#define DIM_W 2048

#define RADIX 256
#define BIN_PTS 2048
#define SEG_TILE 2048

// Sort plan (grouping-exact, deterministic):
//   pass 1 (512 thr): bin by seg = y<<1 | x>>10   (256 bins, global cursors)
//   pass 2 (1024 thr): one block per segment; bin by b8 = (z<<3)|(x>>7 & 7)
//   Final order: (y, x10, z, x9..7) — measured R10-R12: main FETCH 45 MB.

// 4B-aligned vector types for unaligned-row loads (dword-aligned dwordx4)
typedef float float4u __attribute__((ext_vector_type(4), aligned(4)));
typedef int   int4u   __attribute__((ext_vector_type(4), aligned(4)));

__device__ __forceinline__ unsigned seg_of_xy(int x, int y) {
    return ((unsigned)y << 1) | ((unsigned)x >> 10);
}
__device__ __forceinline__ unsigned seg_of_wy(unsigned wy) {
    return (((wy >> 11) & 0x7Fu) << 1) | ((wy >> 10) & 1u);
}
__device__ __forceinline__ unsigned b8_of_wy(unsigned wy) {
    return (((wy >> 18) & 31u) << 3) | ((wy >> 7) & 7u);
}

// ---------------- seg histogram ----------------
__global__ __launch_bounds__(256) void hist0_kernel(
    const int* __restrict__ px, const int* __restrict__ py,
    unsigned* __restrict__ h0, int P)
{
    __shared__ unsigned lh0[RADIX];
    int t = threadIdx.x;
    lh0[t] = 0;
    __syncthreads();
    int base4 = blockIdx.x * 1024 + t;
#pragma unroll
    for (int g = 0; g < 4; ++g) {
        int i4 = base4 + g * 256;
        int i0 = i4 * 4;
        if (i0 + 3 < P) {
            int4 X = ((const int4*)px)[i4];
            int4 Y = ((const int4*)py)[i4];
            atomicAdd(&lh0[seg_of_xy(X.x, Y.x)], 1u);
            atomicAdd(&lh0[seg_of_xy(X.y, Y.y)], 1u);
            atomicAdd(&lh0[seg_of_xy(X.z, Y.z)], 1u);
            atomicAdd(&lh0[seg_of_xy(X.w, Y.w)], 1u);
        } else {
            for (int i = i0; i < P; ++i)
                atomicAdd(&lh0[seg_of_xy(px[i], py[i])], 1u);
        }
    }
    __syncthreads();
    if (lh0[t]) atomicAdd(&h0[t], lh0[t]);
}

// exclusive scan of 256 entries; result to BOTH h (pass-1 cursors) and hbase
__global__ __launch_bounds__(256) void scan256_dup_kernel(
    unsigned* __restrict__ h, unsigned* __restrict__ hbase)
{
    __shared__ unsigned ws[4];
    int t = threadIdx.x, lane = t & 63, wid = t >> 6;
    unsigned a = h[t], ia = a;
#pragma unroll
    for (int off = 1; off < 64; off <<= 1) {
        unsigned v = __shfl_up(ia, off);
        if (lane >= off) ia += v;
    }
    if (lane == 63) ws[wid] = ia;
    __syncthreads();
    unsigned b = 0;
#pragma unroll
    for (int w = 0; w < 4; ++w) b += (w < wid) ? ws[w] : 0u;
    unsigned excl = b + ia - a;
    h[t] = excl;
    hbase[t] = excl;
}

// ---------------- pass 1: bin by seg, 512 threads ----------------
struct BinShared {
    unsigned lh[RADIX];
    unsigned lscan[RADIX];
    unsigned gbase[RADIX];
    unsigned wsum[4];
    uint4 stage[BIN_PTS];   // 32 KB
};

__global__ __launch_bounds__(512) void bin_pass1_kernel(
    const float* __restrict__ ur, const int* __restrict__ px,
    const int* __restrict__ py, const int* __restrict__ pz,
    unsigned* __restrict__ g0, uint4* __restrict__ outp, int P)
{
    __shared__ BinShared S;
    int t = threadIdx.x, lane = t & 63, wid = t >> 6;
    int bstart = blockIdx.x * BIN_PTS;
    int n = min(BIN_PTS, P - bstart);
    if (t < RADIX) S.lh[t] = 0;
    __syncthreads();

    uint4 pay[4];
    unsigned rk[4], dg[4];
    {
        int i4 = (bstart >> 2) + t;
        int i0 = i4 * 4;
        if (i0 + 3 < P) {
            int4 X = ((const int4*)px)[i4];
            int4 Y = ((const int4*)py)[i4];
            int4 Z = ((const int4*)pz)[i4];
            float4 U = ((const float4*)ur)[i4];
            int xs[4] = {X.x, X.y, X.z, X.w};
            int ys[4] = {Y.x, Y.y, Y.z, Y.w};
            int zs[4] = {Z.x, Z.y, Z.z, Z.w};
            float us[4] = {U.x, U.y, U.z, U.w};
#pragma unroll
            for (int c = 0; c < 4; ++c) {
                dg[c] = seg_of_xy(xs[c], ys[c]);
                rk[c] = atomicAdd(&S.lh[dg[c]], 1u);
                pay[c] = make_uint4(__float_as_uint(us[c]),
                    (unsigned)xs[c] | ((unsigned)ys[c] << 11) | ((unsigned)zs[c] << 18),
                    (unsigned)(i0 + c), 0u);
            }
        } else {
#pragma unroll
            for (int c = 0; c < 4; ++c) {
                int gi = i0 + c;
                if (gi < P) {
                    int x = px[gi], y = py[gi], z = pz[gi];
                    dg[c] = seg_of_xy(x, y);
                    rk[c] = atomicAdd(&S.lh[dg[c]], 1u);
                    pay[c] = make_uint4(__float_as_uint(ur[gi]),
                        (unsigned)x | ((unsigned)y << 11) | ((unsigned)z << 18),
                        (unsigned)gi, 0u);
                } else {
                    dg[c] = 0xFFFFFFFFu;
                }
            }
        }
    }
    __syncthreads();

    {
        unsigned c0 = (t < RADIX) ? S.lh[t] : 0u;
        unsigned inc = c0;
#pragma unroll
        for (int off = 1; off < 64; off <<= 1) {
            unsigned v = __shfl_up(inc, off);
            if (lane >= off) inc += v;
        }
        if (t < RADIX && lane == 63) S.wsum[wid] = inc;
        __syncthreads();
        if (t < RADIX) {
            unsigned wb = 0;
#pragma unroll
            for (int w = 0; w < 4; ++w) wb += (w < wid) ? S.wsum[w] : 0u;
            S.lscan[t] = wb + inc - c0;
            S.gbase[t] = c0 ? atomicAdd(&g0[t], c0) : 0u;
        }
    }
    __syncthreads();
#pragma unroll
    for (int c = 0; c < 4; ++c)
        if (dg[c] != 0xFFFFFFFFu)
            S.stage[S.lscan[dg[c]] + rk[c]] = pay[c];
    __syncthreads();
#pragma unroll
    for (int j = 0; j < 4; ++j) {
        int s = j * 512 + t;
        if (s < n) {
            uint4 v = S.stage[s];
            unsigned d = seg_of_wy(v.y);
            unsigned pos = S.gbase[d] + ((unsigned)s - S.lscan[d]);
            outp[pos] = v;
        }
    }
}

// ---------------- pass 2: per-segment (z,x97) scatter, 1024 threads ----------------
__global__ __launch_bounds__(1024) void pass2b_kernel(
    const uint4* __restrict__ inp, const unsigned* __restrict__ segBase,
    uint4* __restrict__ outp, int P)
{
    __shared__ unsigned bh[RADIX];
    __shared__ unsigned cur[RADIX];
    __shared__ unsigned lz[RADIX];
    __shared__ unsigned lsc[RADIX];
    __shared__ unsigned wsum[4];
    __shared__ uint4 stage[SEG_TILE];   // 32 KB

    int b = blockIdx.x;
    unsigned s0 = segBase[b];
    unsigned s1 = (b == RADIX - 1) ? (unsigned)P : segBase[b + 1];
    int t = threadIdx.x, lane = t & 63, wid = t >> 6;

    if (t < RADIX) bh[t] = 0;
    __syncthreads();

    for (unsigned i = s0 + t; i < s1; i += 1024)
        atomicAdd(&bh[b8_of_wy(inp[i].y)], 1u);
    __syncthreads();

    {
        unsigned c0 = (t < RADIX) ? bh[t] : 0u;
        unsigned inc = c0;
#pragma unroll
        for (int off = 1; off < 64; off <<= 1) {
            unsigned v = __shfl_up(inc, off);
            if (lane >= off) inc += v;
        }
        if (t < RADIX && lane == 63) wsum[wid] = inc;
        __syncthreads();
        if (t < RADIX) {
            unsigned wb = 0;
#pragma unroll
            for (int w = 0; w < 4; ++w) wb += (w < wid) ? wsum[w] : 0u;
            cur[t] = s0 + wb + inc - c0;
        }
    }
    __syncthreads();

    for (unsigned tb = s0; tb < s1; tb += SEG_TILE) {
        unsigned m = min((unsigned)SEG_TILE, s1 - tb);
        if (t < RADIX) lz[t] = 0;
        __syncthreads();
        uint4 pay[2];
        unsigned rk[2], zz[2];
#pragma unroll
        for (int j = 0; j < 2; ++j) {
            int s = j * 1024 + t;
            if (s < (int)m) {
                uint4 v = inp[tb + (unsigned)s];
                pay[j] = v;
                zz[j] = b8_of_wy(v.y);
                rk[j] = atomicAdd(&lz[zz[j]], 1u);
            } else {
                zz[j] = 0xFFFFFFFFu;
            }
        }
        __syncthreads();
        {
            unsigned c0 = (t < RADIX) ? lz[t] : 0u;
            unsigned inc = c0;
#pragma unroll
            for (int off = 1; off < 64; off <<= 1) {
                unsigned v = __shfl_up(inc, off);
                if (lane >= off) inc += v;
            }
            if (t < RADIX && lane == 63) wsum[wid] = inc;
            __syncthreads();
            if (t < RADIX) {
                unsigned wb = 0;
#pragma unroll
                for (int w = 0; w < 4; ++w) wb += (w < wid) ? wsum[w] : 0u;
                lsc[t] = wb + inc - c0;
            }
        }
        __syncthreads();
#pragma unroll
        for (int j = 0; j < 2; ++j)
            if (zz[j] != 0xFFFFFFFFu)
                stage[lsc[zz[j]] + rk[j]] = pay[j];
        __syncthreads();
#pragma unroll
        for (int j = 0; j < 2; ++j) {
            int s = j * 1024 + t;
            if (s < (int)m) {
                uint4 v = stage[s];
                unsigned d = b8_of_wy(v.y);
                outp[cur[d] + ((unsigned)s - lsc[d])] = v;
            }
        }
        __syncthreads();
        if (t < RADIX) cur[t] += lz[t];
        __syncthreads();
    }
}

// ---------------- KNN body: class carried through the selection network ----
// All arrays constant-indexed (fully unrolled) -> stay in VGPRs; no
// AMDGPUPromoteAlloca LDS demotion (R13's regression).
__device__ __forceinline__ void bev_knn_body(
    const float* __restrict__ pr, const int* __restrict__ pa,
    float u, int x, int y, int z, int oidx, int* __restrict__ out)
{
    // One 4B-aligned 16B load per (dz,dy) row for BOTH pr and pa, covering
    // x-1..x+2. xo clamped inside the row; uniform shift s remaps lanes:
    //   needed val_j = L[s+j], j=0..2, with L[-1]=L[4]=0 (zero padding).
    int xo = min(max(x - 1, 0), DIM_W - 4);
    int s = x - 1 - xo;             // -1 (x=0), 0 (common), 1 (x=2046), 2 (x=2047)

    float dist[K3];
    int   cls[K3];
#pragma unroll
    for (int r = 0; r < 9; ++r) {
        const int dz = r / 3 - 1;
        const int dy = r % 3 - 1;
        int zz = z + dz, yy = y + dy;
        bool ok = ((unsigned)zz < (unsigned)DIM_D) &
                  ((unsigned)yy < (unsigned)DIM_H);
        int row = ok ? (zz * DIM_H + yy) : 0;
        size_t rb = (((size_t)row) << 11) + xo;
        float4u l = *(const float4u*)(pr + rb);
        int4u   a = *(const int4u*)(pa + rb);
        float a0 = ok ? l.x : 0.f;
        float a1 = ok ? l.y : 0.f;
        float a2 = ok ? l.z : 0.f;
        float a3 = ok ? l.w : 0.f;
        int   c0 = ok ? a.x : 0;
        int   c1 = ok ? a.y : 0;
        int   c2 = ok ? a.z : 0;
        int   c3 = ok ? a.w : 0;
        // v_j / cc_j = L[s+j]
        float v0 = (s == 0) ? a0 : ((s == -1) ? 0.f : ((s == 1) ? a1 : a2));
        float v1 = (s == 0) ? a1 : ((s == -1) ? a0 : ((s == 1) ? a2 : a3));
        float v2 = (s == 0) ? a2 : ((s == -1) ? a1 : ((s == 1) ? a3 : 0.f));
        int  cc0 = (s == 0) ? c0 : ((s == -1) ? 0   : ((s == 1) ? c1 : c2));
        int  cc1 = (s == 0) ? c1 : ((s == -1) ? c0  : ((s == 1) ? c2 : c3));
        int  cc2 = (s == 0) ? c2 : ((s == -1) ? c1  : ((s == 1) ? c3 : 0));
        v0 = (v0 < 0.f) ? INFINITY : v0;
        v1 = (v1 < 0.f) ? INFINITY : v1;
        v2 = (v2 < 0.f) ? INFINITY : v2;
        const int k = r * 3;
        dist[k + 0] = fabsf(v0 - u);
        dist[k + 1] = (k + 1 == CENTER) ? 0.0f : fabsf(v1 - u);
        dist[k + 2] = fabsf(v2 - u);
        cls[k + 0] = cc0;
        cls[k + 1] = cc1;
        cls[k + 2] = cc2;
    }

    // top-5 smallest over (dist, cls) pairs; strict < with ascending k
    // preserves lax.top_k's lowest-index-first tie semantics.
    float bd[KNN];
    int   bc[KNN];
#pragma unroll
    for (int j = 0; j < KNN; ++j) { bd[j] = INFINITY; bc[j] = 0; }
#pragma unroll
    for (int k = 0; k < K3; ++k) {
        float dcur = dist[k];
        int   ccur = cls[k];
#pragma unroll
        for (int j = 0; j < KNN; ++j) {
            bool take = dcur < bd[j];
            float td = bd[j]; int tc = bc[j];
            bd[j] = take ? dcur : bd[j];
            bc[j] = take ? ccur : bc[j];
            dcur  = take ? td : dcur;
            ccur  = take ? tc : ccur;
        }
    }

    // cutoff + majority vote over classes 1..20, ties -> lowest class
    int votes[KNN];
#pragma unroll
    for (int j = 0; j < KNN; ++j)
        votes[j] = (bd[j] > 1.0f) ? NCLASSES : bc[j];

    int best_cnt = 0, best_cls = 1;
#pragma unroll
    for (int j = 0; j < KNN; ++j) {
        int v = votes[j];
        if (v >= 1 && v <= NCLASSES - 1) {
            int cnt = 0;
#pragma unroll
            for (int i = 0; i < KNN; ++i) cnt += (votes[i] == v) ? 1 : 0;
            if (cnt > best_cnt || (cnt == best_cnt && v < best_cls)) {
                best_cnt = cnt;
                best_cls = v;
            }
        }
    }
    out[oidx] = best_cls;
}

__device__ __forceinline__ int swizzle_block(int b, int nb) {
    if ((nb & 7) == 0) {
        int per = nb >> 3;
        return (b & 7) * per + (b >> 3);
    }
    return b;
}

__global__ __launch_bounds__(256) void bev_knn_aos_kernel(
    const float* __restrict__ pr, const int* __restrict__ pa,
    const uint4* __restrict__ payload, int* __restrict__ out, int P)
{
    int lb = swizzle_block(blockIdx.x, gridDim.x);
    int p = lb * blockDim.x + threadIdx.x;
    if (p >= P) return;
    uint4 w = payload[p];
    float u = __uint_as_float(w.x);
    int x = (int)(w.y & 0x7FFu);
    int y = (int)((w.y >> 11) & 0x7Fu);
    int z = (int)((w.y >> 18) & 0x1Fu);
    bev_knn_body(pr, pa, u, x, y, z, (int)w.z, out);
}

__global__ __launch_bounds__(256) void bev_knn_direct_kernel(
    const float* __restrict__ pr, const int* __restrict__ pa,
    const float* __restrict__ ur, const int* __restrict__ px,
    const int* __restrict__ py, const int* __restrict__ pz,
    int* __restrict__ out, int P)
{
    int p = blockIdx.x * blockDim.x + threadIdx.x;
    if (p >= P) return;
    bev_knn_body(pr, pa, ur[p], px[p], py[p], pz[p], p, out);
}

extern "C" void kernel_launch(void* const* d_in, const int* in_sizes, int n_in,
                              void* d_out, int out_size, void* d_ws, size_t ws_size,
                              hipStream_t stream) {
    const float* pr = (const float*)d_in[0];
    const float* ur = (const float*)d_in[1];
    const int*   pa = (const int*)d_in[2];
    const int*   px = (const int*)d_in[3];
    const int*   py = (const int*)d_in[4];
    const int*   pz = (const int*)d_in[5];
    int* out = (int*)d_out;
    int P = in_sizes[1];
    int gridH = (P + 4095) / 4096;
    int gridB = (P + BIN_PTS - 1) / BIN_PTS;
    int gridD = (P + 255) / 256;

    size_t h_b   = (size_t)RADIX * 4;
    size_t hb_b  = (size_t)RADIX * 4;
    size_t p_off = (h_b + hb_b + 15) & ~(size_t)15;
    size_t pay_b = (size_t)P * 16;
    size_t need  = p_off + 2 * pay_b;

    if (ws_size >= need) {
        char* ws = (char*)d_ws;
        unsigned* h0cur  = (unsigned*)ws;
        unsigned* h0base = (unsigned*)(ws + h_b);
        uint4*    pay1   = (uint4*)(ws + p_off);
        uint4*    pay2   = (uint4*)(ws + p_off + pay_b);

        hipMemsetAsync(h0cur, 0, h_b, stream);
        hist0_kernel<<<gridH, 256, 0, stream>>>(px, py, h0cur, P);
        scan256_dup_kernel<<<1, 256, 0, stream>>>(h0cur, h0base);
        bin_pass1_kernel<<<gridB, 512, 0, stream>>>(ur, px, py, pz,
                                                    h0cur, pay1, P);
        pass2b_kernel<<<RADIX, 1024, 0, stream>>>(pay1, h0base, pay2, P);
        bev_knn_aos_kernel<<<gridD, 256, 0, stream>>>(pr, pa, pay2, out, P);
    } else {
        bev_knn_direct_kernel<<<gridD, 256, 0, stream>>>(pr, pa, ur, px, py,
                                                         pz, out, P);
    }
}